// Round 18
// baseline (73.374 us; speedup 1.0000x reference)
//
#include <hip/hip_runtime.h>
#include <stdint.h>
#include <stddef.h>

#define BB 64
#define DIN 1024
#define DD 768
#define CC 1000
#define EPSA 0.1f
#define NSIM 3

typedef short  s16x8 __attribute__((ext_vector_type(8)));
typedef float  f32x4 __attribute__((ext_vector_type(4)));

static __device__ __forceinline__ unsigned short f2bf_rne(float x) {
  unsigned u = __float_as_uint(x);
  return (unsigned short)((u + 0x7FFFu + ((u >> 16) & 1u)) >> 16);
}
static __device__ __forceinline__ float bf2f(unsigned short h) {
  return __uint_as_float(((unsigned)h) << 16);
}

// ---------------------------------------------------------------- prep: pack {W_fc,anchors,W_emb,x} to bf16 frags + An2
// frag[nt][ks][lane][reg]: row = nt*16+(lane&15), k = ks*32+(lane>>4)*8+reg
__global__ __launch_bounds__(256) void prep_kernel(const float* __restrict__ W_fc,
                                                   const float* __restrict__ anchors,
                                                   const float* __restrict__ W_emb,
                                                   const float* __restrict__ x,
                                                   short* __restrict__ Bp, short* __restrict__ Ap,
                                                   short* __restrict__ Ip, short* __restrict__ Xp,
                                                   float* __restrict__ An2) {
  const int blk = blockIdx.x, tid = threadIdx.x;
  if (blk < 1184) {
    const float* src; short* dst; int KS, nrow, gid;
    if (blk < 384)       { src = W_fc;    dst = Bp; KS = 24; nrow = CC;  gid = blk * 256 + tid; }
    else if (blk < 768)  { src = anchors; dst = Ap; KS = 24; nrow = CC;  gid = (blk - 384) * 256 + tid; }
    else if (blk < 1152) { src = W_emb;   dst = Ip; KS = 32; nrow = DD;  gid = (blk - 768) * 256 + tid; }
    else                 { src = x;       dst = Xp; KS = 32; nrow = BB;  gid = (blk - 1152) * 256 + tid; }
    int lane = gid & 63;
    int ks   = (gid >> 6) % KS;
    int nt   = gid / (64 * KS);
    int row  = nt * 16 + (lane & 15);
    int k0   = ks * 32 + (lane >> 4) * 8;
    int stride = KS * 32;
    s16x8 v;
    #pragma unroll
    for (int r = 0; r < 8; ++r) {
      float w = (row < nrow) ? src[(size_t)row * stride + k0 + r] : 0.0f;
      v[r] = (short)f2bf_rne(w);
    }
    ((s16x8*)dst)[gid] = v;
  } else {
    int w = tid >> 6, lane = tid & 63;
    int j = (blk - 1184) * 4 + w;          // < 1000
    const float4* ar = (const float4*)(anchors + (size_t)j * DD);
    float an = 0.f;
    for (int k4 = lane; k4 < DD / 4; k4 += 64) {
      float4 a = ar[k4];
      an += a.x*a.x + a.y*a.y + a.z*a.z + a.w*a.w;
    }
    #pragma unroll
    for (int o = 1; o < 64; o <<= 1) an += __shfl_xor(an, o);
    if (lane == 0) An2[j] = an;
  }
}

// ---------------------------------------------------------------- embV: blocks 0..255 -> Vb + Vp; 256..267 -> emb + Ep
// Fuses the old packmid repacks via LDS staging (bitwise-identical layouts).
__global__ __launch_bounds__(256) void embV_kernel(const short* __restrict__ Bp,
                                                   const short* __restrict__ Ip,
                                                   const short* __restrict__ Xp,
                                                   const float* __restrict__ b_emb,
                                                   unsigned short* __restrict__ Vb,
                                                   short* __restrict__ Vp,
                                                   float* __restrict__ emb,
                                                   short* __restrict__ Ep) {
  const int tid = threadIdx.x, w = tid >> 6, lane = tid & 63;
  __shared__ __attribute__((aligned(16))) short lsh[4608];   // V: [4][16][72], emb: [64][72]
  if (blockIdx.x < 256) {
    const int bx = blockIdx.x & 15, cb = blockIdx.x >> 4;
    const int rnt = bx * 4 + w;
    const s16x8* BH = (const s16x8*)Bp;
    f32x4 acc[4] = {};
    for (int ks = 0; ks < 24; ++ks) {
      s16x8 a = BH[(rnt * 24 + ks) * 64 + lane];
      #pragma unroll
      for (int nf = 0; nf < 4; ++nf)
        acc[nf] = __builtin_amdgcn_mfma_f32_16x16x32_bf16(a, BH[((cb * 4 + nf) * 24 + ks) * 64 + lane], acc[nf], 0, 0, 0);
    }
    const int rl0 = (lane >> 4) * 4;             // C/D: row=(lane>>4)*4+reg, col=lane&15 [m89]
    const int r0 = rnt * 16 + rl0;
    const int c0 = cb * 64 + (lane & 15);
    #pragma unroll
    for (int nf = 0; nf < 4; ++nf)
      #pragma unroll
      for (int rr = 0; rr < 4; ++rr) {
        unsigned short h = f2bf_rne(acc[nf][rr]);
        Vb[(size_t)(r0 + rr) * 1024 + c0 + nf * 16] = h;
        lsh[w * 1152 + (rl0 + rr) * 72 + (lane & 15) + nf * 16] = (short)h;
      }
    __syncthreads();
    #pragma unroll
    for (int ksh = 0; ksh < 2; ++ksh) {
      int ks = cb * 2 + ksh;
      s16x8 v = *(const s16x8*)&lsh[w * 1152 + (lane & 15) * 72 + ksh * 32 + (lane >> 4) * 8];
      ((s16x8*)Vp)[(rnt * 32 + ks) * 64 + lane] = v;
    }
  } else {
    const int g = blockIdx.x - 256;             // 0..11
    const int nfr = g * 4 + w;                  // 0..47
    const s16x8* XH = (const s16x8*)Xp;
    const s16x8* IH = (const s16x8*)Ip;
    f32x4 acc[4] = {};
    for (int ks = 0; ks < 32; ++ks) {
      s16x8 b = IH[(nfr * 32 + ks) * 64 + lane];
      #pragma unroll
      for (int mt = 0; mt < 4; ++mt)
        acc[mt] = __builtin_amdgcn_mfma_f32_16x16x32_bf16(XH[(mt * 32 + ks) * 64 + lane], b, acc[mt], 0, 0, 0);
    }
    const int d = nfr * 16 + (lane & 15);       // < 768
    const int dl = w * 16 + (lane & 15);        // 0..63 within block's d-tile
    const float be = b_emb[d];
    #pragma unroll
    for (int mt = 0; mt < 4; ++mt)
      #pragma unroll
      for (int rr = 0; rr < 4; ++rr) {
        int b = mt * 16 + (lane >> 4) * 4 + rr;
        float ev = acc[mt][rr] + be;
        emb[(size_t)b * DD + d] = ev;
        lsh[b * 72 + dl] = (short)f2bf_rne(ev);
      }
    __syncthreads();
    #pragma unroll
    for (int ksh = 0; ksh < 2; ++ksh) {
      int ks = g * 2 + ksh;                     // 0..23
      int mt2 = tid >> 6;                       // reuse w
      s16x8 v = *(const s16x8*)&lsh[(mt2 * 16 + (lane & 15)) * 72 + ksh * 32 + (lane >> 4) * 8];
      ((s16x8*)Ep)[(mt2 * 24 + ks) * 64 + lane] = v;
    }
  }
}

// ---------------------------------------------------------------- logits + AE via MFMA (grid 64 x 4, 1 wave)
__global__ __launch_bounds__(64) void logitsAE_kernel(const short* __restrict__ Ep,
                                                      const short* __restrict__ Bp,
                                                      const short* __restrict__ Ap,
                                                      const float* __restrict__ b_fc,
                                                      float* __restrict__ logits,
                                                      float* __restrict__ AE) {
  const int nfr = blockIdx.x;                  // 0..63
  const int mt  = blockIdx.y;                  // 0..3
  const int lane = threadIdx.x;
  const s16x8* E = (const s16x8*)Ep;
  const s16x8* B = (const s16x8*)Bp;
  const s16x8* A = (const s16x8*)Ap;
  f32x4 accL = {}, accA = {};
  for (int ks = 0; ks < 24; ++ks) {
    s16x8 a  = E[(mt * 24 + ks) * 64 + lane];
    s16x8 bW = B[(nfr * 24 + ks) * 64 + lane];
    s16x8 bA = A[(nfr * 24 + ks) * 64 + lane];
    accL = __builtin_amdgcn_mfma_f32_16x16x32_bf16(a, bW, accL, 0, 0, 0);
    accA = __builtin_amdgcn_mfma_f32_16x16x32_bf16(a, bA, accA, 0, 0, 0);
  }
  const int c = nfr * 16 + (lane & 15);
  if (c < CC) {
    const float bf = b_fc[c];
    #pragma unroll
    for (int rr = 0; rr < 4; ++rr) {
      int b = mt * 16 + (lane >> 4) * 4 + rr;
      logits[b * CC + c] = accL[rr] + bf;
      AE[b * CC + c]     = accA[rr];
    }
  }
}

// ---------------------------------------------------------------- softmax + argmax + En2 + Pp (bf16 frag of p)
__global__ __launch_bounds__(256) void softmax_kernel(const float* __restrict__ logits,
                                                      const float* __restrict__ emb,
                                                      float* __restrict__ p,
                                                      short* __restrict__ Pp,
                                                      int* __restrict__ pred,
                                                      float* __restrict__ En2) {
  int b = blockIdx.x, t = threadIdx.x;
  __shared__ float smax[256];
  __shared__ int   sidx[256];
  __shared__ float ssum[256];
  {
    float pe = 0.f;
    for (int k = t; k < DD; k += 256) { float e = emb[b * DD + k]; pe += e * e; }
    #pragma unroll
    for (int o = 1; o < 64; o <<= 1) pe += __shfl_xor(pe, o);
    __shared__ float se[4];
    if ((t & 63) == 0) se[t >> 6] = pe;
    __syncthreads();
    if (t == 0) En2[b] = se[0] + se[1] + se[2] + se[3];
  }
  float m = -3.402823466e38f; int mi = 0;
  for (int c = t; c < CC; c += 256) {
    float v = logits[b * CC + c];
    if (v > m) { m = v; mi = c; }
  }
  smax[t] = m; sidx[t] = mi;
  __syncthreads();
  for (int o = 128; o > 0; o >>= 1) {
    if (t < o) {
      float v2 = smax[t + o]; int i2 = sidx[t + o];
      if (v2 > smax[t] || (v2 == smax[t] && i2 < sidx[t])) { smax[t] = v2; sidx[t] = i2; }
    }
    __syncthreads();
  }
  float M = smax[0];
  if (t == 0) pred[b] = sidx[0];
  float sum = 0.f;
  for (int c = t; c < CC; c += 256) sum += expf(logits[b * CC + c] - M);
  ssum[t] = sum;
  __syncthreads();
  for (int o = 128; o > 0; o >>= 1) {
    if (t < o) ssum[t] += ssum[t + o];
    __syncthreads();
  }
  float S = ssum[0];
  const int mt = b >> 4, blo = b & 15;
  for (int j = t; j < CC; j += 256) {
    float pj = expf(logits[b * CC + j] - M) / S;
    p[b * CC + j] = pj;
    size_t fi = ((size_t)(mt * 32 + (j >> 5)) * 64 + ((j >> 3) & 3) * 16 + blo) * 8 + (j & 7);
    Pp[fi] = (short)f2bf_rne(pj);
  }
  if (t < 24) {     // zero k-pad 1000..1023
    int j = 1000 + t;
    size_t fi = ((size_t)(mt * 32 + (j >> 5)) * 64 + ((j >> 3) & 3) * 16 + blo) * 8 + (j & 7);
    Pp[fi] = 0;
  }
}

// ---------------------------------------------------------------- u = p @ V via MFMA (grid 64 x 4, 1 wave)
__global__ __launch_bounds__(64) void u_kernel(const short* __restrict__ Pp,
                                               const short* __restrict__ Vp,
                                               float* __restrict__ u) {
  const int nfr = blockIdx.x;                  // 0..63
  const int mt  = blockIdx.y;                  // 0..3
  const int lane = threadIdx.x;
  const s16x8* P = (const s16x8*)Pp;
  const s16x8* V = (const s16x8*)Vp;
  f32x4 acc = {};
  for (int ks = 0; ks < 32; ++ks) {
    s16x8 b = V[(nfr * 32 + ks) * 64 + lane];
    acc = __builtin_amdgcn_mfma_f32_16x16x32_bf16(P[(mt * 32 + ks) * 64 + lane], b, acc, 0, 0, 0);
  }
  const int c = nfr * 16 + (lane & 15);
  if (c < CC) {
    #pragma unroll
    for (int rr = 0; rr < 4; ++rr)
      u[(mt * 16 + (lane >> 4) * 4 + rr) * CC + c] = acc[rr];
  }
}

// ---------------------------------------------------------------- scan v3: thread owns 4 j's; c-slice of 63; no reductions
// grid (64, 16): block = (b, c-slice). V[j,c] = V[c,j] (symmetric) -> coalesced uint2 per c.
__global__ __launch_bounds__(256) void scan_kernel(const float* __restrict__ logits,
                                                   const float* __restrict__ u,
                                                   const float* __restrict__ p,
                                                   const float* __restrict__ AE,
                                                   const float* __restrict__ An2,
                                                   const float* __restrict__ En2,
                                                   const unsigned short* __restrict__ Vb,
                                                   unsigned long long* __restrict__ part) {
  const int b = blockIdx.x, cz = blockIdx.y;   // cz < 16
  const int tid = threadIdx.x;
  const int c0 = cz * 63;
  const int cend = (CC - c0 < 63) ? (CC - c0) : 63;   // 55 for cz=15
  __shared__ __attribute__((aligned(8))) float2 LU[64];
  __shared__ float se[4];

  if (tid < cend) {
    int c = c0 + tid;
    LU[tid] = float2{logits[b * CC + c], u[b * CC + c]};
  }
  // Gn2 = sum_c p*u (fixed-order tree -> identical across all cz blocks)
  float partsum = 0.f;
  {
    int cg = tid * 4;
    if (cg + 3 < CC) {
      float4 p4 = *(const float4*)(p + b * CC + cg);
      float4 u4 = *(const float4*)(u + b * CC + cg);
      partsum = p4.x*u4.x + p4.y*u4.y + p4.z*u4.z + p4.w*u4.w;
    } else {
      #pragma unroll
      for (int i = 0; i < 4; ++i) {
        int c = cg + i;
        if (c < CC) partsum += p[b * CC + c] * u[b * CC + c];
      }
    }
  }
  #pragma unroll
  for (int o = 1; o < 64; o <<= 1) partsum += __shfl_xor(partsum, o);
  if ((tid & 63) == 0) se[tid >> 6] = partsum;
  __syncthreads();
  const float gn2b = se[0] + se[1] + se[2] + se[3];
  const float en2 = En2[b];

  // this thread's 4 j's (threads 250..255 duplicate 249, don't write)
  const int jt = (tid < 250 ? tid : 249) * 4;
  float4 an4 = *(const float4*)(An2 + jt);
  float4 ae4 = *(const float4*)(AE + b * CC + jt);
  float4 uj4 = *(const float4*)(u + b * CC + jt);
  float sj[4], nsj[4];
  {
    float anv[4] = {an4.x, an4.y, an4.z, an4.w};
    float aev[4] = {ae4.x, ae4.y, ae4.z, ae4.w};
    float ujv[4] = {uj4.x, uj4.y, uj4.z, uj4.w};
    #pragma unroll
    for (int k = 0; k < 4; ++k) {
      float vd  = bf2f(Vb[(size_t)(jt + k) * 1024 + jt + k]);
      float zn2 = anv[k] - 2.0f * aev[k] + en2;
      float gn2 = gn2b - 2.0f * ujv[k] + vd;
      sj[k] = (EPSA * sqrtf(zn2)) / sqrtf(gn2);
      nsj[k] = -sj[k];
    }
  }

  float best[4] = {-3.402823466e38f, -3.402823466e38f, -3.402823466e38f, -3.402823466e38f};
  int   bi[4]   = {0, 0, 0, 0};
  const unsigned short* Vcol = Vb + jt;
  #pragma unroll 7
  for (int i = 0; i < cend; ++i) {
    int c = c0 + i;
    float2 lu = LU[i];                                   // broadcast (lane-uniform)
    uint2 vv = *(const uint2*)(Vcol + (size_t)c * 1024); // V[c][jt..jt+3], coalesced
    float v0 = __uint_as_float(vv.x << 16);
    float v1 = __uint_as_float(vv.x & 0xffff0000u);
    float v2 = __uint_as_float(vv.y << 16);
    float v3 = __uint_as_float(vv.y & 0xffff0000u);
    float t0 = fmaf(sj[0], lu.y, lu.x);
    float t1 = fmaf(sj[1], lu.y, lu.x);
    float t2 = fmaf(sj[2], lu.y, lu.x);
    float t3 = fmaf(sj[3], lu.y, lu.x);
    float val0 = fmaf(nsj[0], v0, t0);
    float val1 = fmaf(nsj[1], v1, t1);
    float val2 = fmaf(nsj[2], v2, t2);
    float val3 = fmaf(nsj[3], v3, t3);
    if (val0 > best[0]) { best[0] = val0; bi[0] = c; }   // ascending c + strict > = first max
    if (val1 > best[1]) { best[1] = val1; bi[1] = c; }
    if (val2 > best[2]) { best[2] = val2; bi[2] = c; }
    if (val3 > best[3]) { best[3] = val3; bi[3] = c; }
  }

  if (tid < 250) {
    unsigned long long* dst = part + (size_t)cz * 64000 + b * 1000 + jt;
    #pragma unroll
    for (int k = 0; k < 4; ++k) {
      unsigned ub = __float_as_uint(best[k]);
      ub = (ub & 0x80000000u) ? ~ub : (ub | 0x80000000u);
      dst[k] = ((unsigned long long)ub << 32) |
               (unsigned long long)(0xFFFFFFFFu - (unsigned)bi[k]);   // tie -> smaller c
    }
  }
}

// ---------------------------------------------------------------- counts: merge 16 c-slices + all(counts < 3)
__global__ __launch_bounds__(256) void counts_kernel(const unsigned long long* __restrict__ part,
                                                     const int* __restrict__ pred,
                                                     float* __restrict__ out) {
  int b = blockIdx.x, t = threadIdx.x;
  __shared__ int cnt[CC];
  __shared__ int bad;
  for (int c = t; c < CC; c += 256) cnt[c] = 0;
  if (t == 0) bad = 0;
  __syncthreads();
  if (t == 0) atomicAdd(&cnt[pred[b]], 1);
  const unsigned long long* pr = part + b * 1000;
  for (int j = t; j < CC; j += 256) {
    unsigned long long key = 0;
    #pragma unroll
    for (int cz = 0; cz < 16; ++cz) {
      unsigned long long k2 = pr[(size_t)cz * 64000 + j];
      key = (k2 > key) ? k2 : key;
    }
    int c = (int)(0xFFFFFFFFu - (unsigned)(key & 0xFFFFFFFFull));
    atomicAdd(&cnt[c], 1);
  }
  __syncthreads();
  for (int c = t; c < CC; c += 256) if (cnt[c] >= NSIM) bad = 1;
  __syncthreads();
  if (t == 0) out[b] = bad ? 0.0f : 1.0f;
}

// ---------------------------------------------------------------- launch
extern "C" void kernel_launch(void* const* d_in, const int* in_sizes, int n_in,
                              void* d_out, int out_size, void* d_ws, size_t ws_size,
                              hipStream_t stream) {
  const float* x       = (const float*)d_in[0];
  const float* W_emb   = (const float*)d_in[1];
  const float* b_emb   = (const float*)d_in[2];
  const float* W_fc    = (const float*)d_in[3];
  const float* b_fc    = (const float*)d_in[4];
  const float* anchors = (const float*)d_in[5];
  float* out = (float*)d_out;

  // workspace carve (~18.4 MB), all aligned
  float* emb    = (float*)d_ws;               // 64*768
  float* logits = emb + BB * DD;              // 64*1000
  float* p      = logits + BB * CC;           // 64*1000
  float* u      = p + BB * CC;                // 64*1000
  float* AE     = u + BB * CC;                // 64*1000
  float* An2    = AE + BB * CC;               // 1024
  float* En2    = An2 + 1024;                 // 64
  int*   pred   = (int*)(En2 + 64);           // 64
  unsigned long long* part = (unsigned long long*)(pred + 64);   // 16*64000 u64 (8.2 MB)
  short* Bp     = (short*)(part + 16 * 64000);// 786432 shorts
  short* Ap     = Bp + 64 * 24 * 64 * 8;      // 786432
  short* Ip     = Ap + 64 * 24 * 64 * 8;      // 786432
  short* Xp     = Ip + 48 * 32 * 64 * 8;      // 65536
  short* Ep     = Xp + 4 * 32 * 64 * 8;       // 49152
  short* Pp     = Ep + 4 * 24 * 64 * 8;       // 65536
  unsigned short* Vb = (unsigned short*)(Pp + 4 * 32 * 64 * 8);  // 1024*1024
  short* Vp     = (short*)(Vb + 1024 * 1024); // 1048576

  hipLaunchKernelGGL(prep_kernel,    dim3(1434), dim3(256), 0, stream,
                     W_fc, anchors, W_emb, x, Bp, Ap, Ip, Xp, An2);
  hipLaunchKernelGGL(embV_kernel,    dim3(268), dim3(256), 0, stream,
                     Bp, Ip, Xp, b_emb, Vb, Vp, emb, Ep);
  hipLaunchKernelGGL(logitsAE_kernel,dim3(64, 4), dim3(64), 0, stream, Ep, Bp, Ap, b_fc, logits, AE);
  hipLaunchKernelGGL(softmax_kernel, dim3(BB), dim3(256), 0, stream, logits, emb, p, Pp, pred, En2);
  hipLaunchKernelGGL(u_kernel,       dim3(64, 4), dim3(64), 0, stream, Pp, Vp, u);
  hipLaunchKernelGGL(scan_kernel,    dim3(BB, 16), dim3(256), 0, stream,
                     logits, u, p, AE, An2, En2, Vb, part);
  hipLaunchKernelGGL(counts_kernel,  dim3(BB), dim3(256), 0, stream, part, pred, out);
}